// Round 4
// baseline (1717.141 us; speedup 1.0000x reference)
//
#include <hip/hip_runtime.h>
#include <math.h>

#define BB 8
#define NN 2048
#define DD 256
#define NP 2049
#define E1 0.36787944117144233f
#define PADK 40
#define NBLK 256      // persistent blocks (1 per CU)
#define BPB 32        // blocks per batch
#define NW 16         // waves per block
#define RPW 4         // rows per wave
#define ITERS 20

typedef __attribute__((ext_vector_type(8))) short bf16x8;
typedef __attribute__((ext_vector_type(4))) float f32x4;
typedef __attribute__((ext_vector_type(2))) float f32x2;

#define DEC0(DW) __builtin_amdgcn_cvt_pk_f32_fp8((int)(DW), false)
#define DEC1(DW) __builtin_amdgcn_cvt_pk_f32_fp8((int)(DW), true)

__device__ __forceinline__ unsigned short f2bf(float x) {
    unsigned int u = __builtin_bit_cast(unsigned int, x);
    unsigned int r = (u + 0x7FFFu + ((u >> 16) & 1u)) >> 16;
    return (unsigned short)r;
}
__device__ __forceinline__ float bf2f(unsigned short h) {
    unsigned int u = ((unsigned int)h) << 16;
    return __builtin_bit_cast(float, u);
}

// ---------------- norms: n[b][r] = sum_d d[b][r][d]^2 ----------------
__global__ __launch_bounds__(256) void norms_k(const float* __restrict__ d1,
                                               const float* __restrict__ d2,
                                               float* __restrict__ n1,
                                               float* __restrict__ n2) {
    const float* d = blockIdx.z ? d2 : d1;
    float* nn = blockIdx.z ? n2 : n1;
    int b = blockIdx.y;
    int wave = threadIdx.x >> 6, lane = threadIdx.x & 63;
    int row = blockIdx.x * 4 + wave;
    const float4 v = *(const float4*)(d + ((size_t)b * NN + row) * DD + lane * 4);
    float s = v.x * v.x + v.y * v.y + v.z * v.z + v.w * v.w;
    #pragma unroll
    for (int off = 1; off < 64; off <<= 1) s += __shfl_xor(s, off);
    if (lane == 0) nn[b * NN + row] = s;
}

// ======== MFMA: K core (fp8 e4m3) = exp(-max(n1+n2-2*dot,0)) =========
__global__ __launch_bounds__(256) void gemm_mfma(const float* __restrict__ d1,
                                                 const float* __restrict__ d2,
                                                 const float* __restrict__ n1,
                                                 const float* __restrict__ n2,
                                                 unsigned char* __restrict__ Kc) {
    __shared__ unsigned short Ah[128 * PADK];
    __shared__ unsigned short Al[128 * PADK];
    __shared__ unsigned short Bh[128 * PADK];
    __shared__ unsigned short Bl[128 * PADK];

    const int b = blockIdx.z;
    const int n0 = blockIdx.y * 128, m0 = blockIdx.x * 128;
    const int t = threadIdx.x;
    const int wave = t >> 6, lane = t & 63;
    const int wr = (wave >> 1) * 64;
    const int wc = (wave & 1) * 64;
    const float* A  = d1 + ((size_t)b * NN + n0) * DD;
    const float* Bm = d2 + ((size_t)b * NN + m0) * DD;

    const int lrow = t >> 3;
    const int lk   = (t & 7) * 4;

    f32x4 zero = {0.f, 0.f, 0.f, 0.f};
    f32x4 acc[4][4];
    #pragma unroll
    for (int i = 0; i < 4; ++i)
        #pragma unroll
        for (int j = 0; j < 4; ++j) acc[i][j] = zero;

    const int rb = lane & 15;
    const int kg = (lane >> 4) * 8;

    for (int k0 = 0; k0 < DD; k0 += 32) {
        __syncthreads();
        #pragma unroll
        for (int rr = 0; rr < 4; ++rr) {
            int row = lrow + rr * 32;
            float4 a4 = *(const float4*)(A  + (size_t)row * DD + k0 + lk);
            float4 b4 = *(const float4*)(Bm + (size_t)row * DD + k0 + lk);
            ushort4 h, l;
            h.x = f2bf(a4.x); l.x = f2bf(a4.x - bf2f(h.x));
            h.y = f2bf(a4.y); l.y = f2bf(a4.y - bf2f(h.y));
            h.z = f2bf(a4.z); l.z = f2bf(a4.z - bf2f(h.z));
            h.w = f2bf(a4.w); l.w = f2bf(a4.w - bf2f(h.w));
            *(ushort4*)&Ah[row * PADK + lk] = h;
            *(ushort4*)&Al[row * PADK + lk] = l;
            h.x = f2bf(b4.x); l.x = f2bf(b4.x - bf2f(h.x));
            h.y = f2bf(b4.y); l.y = f2bf(b4.y - bf2f(h.y));
            h.z = f2bf(b4.z); l.z = f2bf(b4.z - bf2f(h.z));
            h.w = f2bf(b4.w); l.w = f2bf(b4.w - bf2f(h.w));
            *(ushort4*)&Bh[row * PADK + lk] = h;
            *(ushort4*)&Bl[row * PADK + lk] = l;
        }
        __syncthreads();

        bf16x8 ah[4], al[4], bh[4], bl[4];
        #pragma unroll
        for (int f = 0; f < 4; ++f) {
            int ar = (wr + f * 16 + rb) * PADK + kg;
            int br = (wc + f * 16 + rb) * PADK + kg;
            ah[f] = *(const bf16x8*)&Ah[ar];
            al[f] = *(const bf16x8*)&Al[ar];
            bh[f] = *(const bf16x8*)&Bh[br];
            bl[f] = *(const bf16x8*)&Bl[br];
        }
        #pragma unroll
        for (int i = 0; i < 4; ++i)
            #pragma unroll
            for (int j = 0; j < 4; ++j) {
                acc[i][j] = __builtin_amdgcn_mfma_f32_16x16x32_bf16(ah[i], bh[j], acc[i][j], 0, 0, 0);
                acc[i][j] = __builtin_amdgcn_mfma_f32_16x16x32_bf16(ah[i], bl[j], acc[i][j], 0, 0, 0);
                acc[i][j] = __builtin_amdgcn_mfma_f32_16x16x32_bf16(al[i], bh[j], acc[i][j], 0, 0, 0);
            }
    }

    const int rloc0 = (lane >> 4) * 4;
    #pragma unroll
    for (int i = 0; i < 4; ++i) {
        #pragma unroll
        for (int jj = 0; jj < 4; ++jj) {
            int r = wr + i * 16 + rloc0 + jj;
            float rn = n1[b * NN + n0 + r];
            unsigned char* orow = Kc + ((size_t)b * NN + n0 + r) * NN + m0;
            #pragma unroll
            for (int j = 0; j < 4; ++j) {
                int c = wc + j * 16 + rb;
                float cn = n2[b * NN + m0 + c];
                float val = __expf(-fmaxf(rn + cn - 2.f * acc[i][j][jj], 0.f));
                int p = __builtin_amdgcn_cvt_pk_fp8_f32(val, val, 0, false);
                orow[c] = (unsigned char)(p & 0xFF);
            }
        }
    }
}

// ---------------- grid barrier (cumulative counter) ------------------
__device__ __forceinline__ void grid_barrier(unsigned int* cnt, unsigned int target) {
    __syncthreads();
    if (threadIdx.x == 0) {
        __threadfence();
        __hip_atomic_fetch_add(cnt, 1u, __ATOMIC_RELEASE, __HIP_MEMORY_SCOPE_AGENT);
        while (__hip_atomic_load(cnt, __ATOMIC_RELAXED, __HIP_MEMORY_SCOPE_AGENT) < target) {
            __builtin_amdgcn_s_sleep(2);
        }
        __builtin_amdgcn_fence(__ATOMIC_ACQUIRE, "agent");
    }
    __syncthreads();
}

// ========== persistent Sinkhorn: 20 iterations + finalize ============
__global__ __launch_bounds__(1024) void sinkhorn_persist(
    const unsigned char* __restrict__ Kc,   // [BB][NN][NN] fp8
    float* __restrict__ part,               // [2][BB][BPB][NN]
    float* __restrict__ asum,               // [2][BB][BPB]
    unsigned int* __restrict__ barcnt,
    float* __restrict__ out)                // [BB][NP][NP]
{
    __shared__ float b_sh[NN];
    __shared__ float cp_sh[NW][2052];
    __shared__ float red_sh[NW];
    __shared__ float asum_sh[NW];
    __shared__ float sc_sh[4];

    const int bid = blockIdx.x;
    const int batch = bid >> 5;
    const int blk = bid & 31;
    const int t = threadIdx.x;
    const int w = t >> 6;
    const int lane = t & 63;
    const int r0 = blk * (NW * RPW) + w * RPW;

    const unsigned char* Kbase = Kc + (size_t)batch * NN * NN;

    float aN = 0.f;         // a_N^{(it)} carried across iterations
    float a_reg[RPW];       // wave's row a-values (persist to finalize)
    float bM = 1.f;

    for (int it = 0; it <= ITERS; ++it) {
        // ---- reconstruct b^{(it)} into b_sh; compute bM, Sb; update aN ----
        if (it == 0) {
            b_sh[t] = 1.f;
            b_sh[t + 1024] = 1.f;
            float sb = 2.f;
            #pragma unroll
            for (int off = 1; off < 64; off <<= 1) sb += __shfl_xor(sb, off);
            if (lane == 0) red_sh[w] = sb;
            if (t == 0) sc_sh[0] = 1.f;          // bM = 1
        } else {
            const int par = (it - 1) & 1;
            const float* as = asum + ((size_t)par * BB + batch) * BPB;
            if (w == 0) {                        // bM = 2048/(E1*(Sa + aN))
                float sa = (lane < BPB) ? as[lane] : 0.f;
                #pragma unroll
                for (int off = 1; off < 64; off <<= 1) sa += __shfl_xor(sa, off);
                if (lane == 0) sc_sh[0] = 2048.f / (E1 * (sa + aN));
            }
            const float* pp = part + ((size_t)par * BB + batch) * (size_t)BPB * NN;
            float cs0 = 0.f, cs1 = 0.f;
            #pragma unroll 8
            for (int k = 0; k < BPB; ++k) {
                f32x2 v = *(const f32x2*)&pp[(size_t)k * NN + 2 * t];
                cs0 += v.x; cs1 += v.y;
            }
            float ea = E1 * aN;
            float b0 = 1.0f / (cs0 + ea);
            float b1 = 1.0f / (cs1 + ea);
            b_sh[2 * t] = b0;
            b_sh[2 * t + 1] = b1;
            float sb = b0 + b1;
            #pragma unroll
            for (int off = 1; off < 64; off <<= 1) sb += __shfl_xor(sb, off);
            if (lane == 0) red_sh[w] = sb;
        }
        __syncthreads();
        bM = sc_sh[0];
        float Sb = bM;
        #pragma unroll
        for (int k = 0; k < NW; ++k) Sb += red_sh[k];
        if (it < ITERS) aN = 2048.f / (E1 * Sb);   // a_N^{(it+1)}

        if (it < ITERS) {
            // ---- row phase: a = 1/(K.b + E1*bM); col partials ----
            f32x4 bv[8];
            #pragma unroll
            for (int j = 0; j < 8; ++j) bv[j] = *(const f32x4*)&b_sh[lane * 32 + j * 4];
            f32x4 cp[8];
            f32x4 zero = {0.f, 0.f, 0.f, 0.f};
            #pragma unroll
            for (int j = 0; j < 8; ++j) cp[j] = zero;
            float asum_loc = 0.f;

            #pragma unroll
            for (int r = 0; r < RPW; ++r) {
                const uint4* rowp = (const uint4*)(Kbase + (size_t)(r0 + r) * NN);
                uint4 ka = rowp[lane * 2];
                uint4 kb = rowp[lane * 2 + 1];
                unsigned int dw[8] = {ka.x, ka.y, ka.z, ka.w, kb.x, kb.y, kb.z, kb.w};
                float rs = 0.f;
                #pragma unroll
                for (int j = 0; j < 8; ++j) {
                    f32x2 u0 = DEC0(dw[j]);
                    f32x2 u1 = DEC1(dw[j]);
                    rs += u0.x * bv[j].x + u0.y * bv[j].y + u1.x * bv[j].z + u1.y * bv[j].w;
                }
                #pragma unroll
                for (int off = 1; off < 64; off <<= 1) rs += __shfl_xor(rs, off);
                float ar = 1.0f / (rs + E1 * bM);
                a_reg[r] = ar;
                asum_loc += ar;
                #pragma unroll
                for (int j = 0; j < 8; ++j) {
                    f32x2 u0 = DEC0(dw[j]);
                    f32x2 u1 = DEC1(dw[j]);
                    cp[j].x += u0.x * ar; cp[j].y += u0.y * ar;
                    cp[j].z += u1.x * ar; cp[j].w += u1.y * ar;
                }
            }
            // swizzled LDS merge of column partials
            #pragma unroll
            for (int j = 0; j < 8; ++j) {
                int jj = j ^ (lane & 7);
                *(f32x4*)&cp_sh[w][lane * 32 + (jj << 2)] = cp[j];
            }
            if (lane == 0) asum_sh[w] = asum_loc;
            __syncthreads();
            {
                int c0 = 2 * t;
                int l0 = c0 >> 5, i0 = c0 & 31, j0 = i0 >> 2, e0 = i0 & 3;
                int loc = l0 * 32 + ((j0 ^ (l0 & 7)) << 2) + e0;
                float s0 = 0.f, s1 = 0.f;
                #pragma unroll
                for (int k = 0; k < NW; ++k) { s0 += cp_sh[k][loc]; s1 += cp_sh[k][loc + 1]; }
                float* pw = part + (((size_t)(it & 1) * BB + batch) * (size_t)BPB + blk) * NN;
                f32x2 sv; sv.x = s0; sv.y = s1;
                *(f32x2*)&pw[c0] = sv;
                if (t == 0) {
                    float s = 0.f;
                    #pragma unroll
                    for (int k = 0; k < NW; ++k) s += asum_sh[k];
                    asum[((size_t)(it & 1) * BB + batch) * BPB + blk] = s;
                }
            }
            grid_barrier(barcnt, (unsigned int)(it + 1) * NBLK);
        } else {
            // ---- finalize: P = a_n * K * b_m ----
            f32x4 bv[8];
            #pragma unroll
            for (int j = 0; j < 8; ++j) bv[j] = *(const f32x4*)&b_sh[lane * 32 + j * 4];
            float* ob = out + (size_t)batch * NP * NP;
            #pragma unroll
            for (int r = 0; r < RPW; ++r) {
                int row = r0 + r;
                const uint4* rowp = (const uint4*)(Kbase + (size_t)row * NN);
                uint4 ka = rowp[lane * 2];
                uint4 kb = rowp[lane * 2 + 1];
                unsigned int dw[8] = {ka.x, ka.y, ka.z, ka.w, kb.x, kb.y, kb.z, kb.w};
                float ar = a_reg[r];
                #pragma unroll
                for (int j = 0; j < 8; ++j) {
                    f32x2 u0 = DEC0(dw[j]);
                    f32x2 u1 = DEC1(dw[j]);
                    f32x4 pv;
                    pv.x = ar * u0.x * bv[j].x;
                    pv.y = ar * u0.y * bv[j].y;
                    pv.z = ar * u1.x * bv[j].z;
                    pv.w = ar * u1.y * bv[j].w;
                    int jj = j ^ (lane & 7);
                    *(f32x4*)&cp_sh[w][lane * 32 + (jj << 2)] = pv;
                }
                float* orow = ob + (size_t)row * NP;
                #pragma unroll
                for (int c = 0; c < 32; ++c) {
                    int col = c * 64 + lane;
                    int l0 = col >> 5, i0 = col & 31, j0 = i0 >> 2, e0 = i0 & 3;
                    orow[col] = cp_sh[w][l0 * 32 + ((j0 ^ (l0 & 7)) << 2) + e0];
                }
                if (lane == 0) orow[NN] = ar * E1 * bM;
            }
            if (blk == 0) {
                float* drow = ob + (size_t)NN * NP;
                float ea = aN * E1;
                drow[2 * t] = ea * b_sh[2 * t];
                drow[2 * t + 1] = ea * b_sh[2 * t + 1];
                if (t == 0) drow[NN] = ea * bM;
            }
        }
    }
}

// =====================================================================
extern "C" void kernel_launch(void* const* d_in, const int* in_sizes, int n_in,
                              void* d_out, int out_size, void* d_ws, size_t ws_size,
                              hipStream_t stream) {
    const float* d1 = (const float*)d_in[0];
    const float* d2 = (const float*)d_in[1];
    float* out = (float*)d_out;

    const size_t KCB = (size_t)BB * NN * NN;            // 33.5 MB fp8
    unsigned char* Kc = (unsigned char*)d_ws;
    float* part = (float*)(Kc + KCB);                   // 2*BB*BPB*NN floats
    float* asum = part + (size_t)2 * BB * BPB * NN;     // 2*BB*BPB
    float* n1 = asum + 2 * BB * BPB;                    // BB*NN
    float* n2 = n1 + BB * NN;                           // BB*NN
    unsigned int* barcnt = (unsigned int*)(n2 + BB * NN);

    hipMemsetAsync(barcnt, 0, 64, stream);
    norms_k<<<dim3(NN / 4, BB, 2), 256, 0, stream>>>(d1, d2, n1, n2);
    gemm_mfma<<<dim3(16, 16, BB), 256, 0, stream>>>(d1, d2, n1, n2, Kc);
    sinkhorn_persist<<<NBLK, 1024, 0, stream>>>(Kc, part, asum, barcnt, out);
}

// Round 5
// 108.880 us; speedup vs baseline: 15.7710x; 15.7710x over previous
//
#include <hip/hip_runtime.h>
#include <math.h>

#define BB 8
#define NN 2048
#define DD 256
#define NP 2049
#define AVP 2052        // padded a/b vector stride (16B-aligned rows)
#define E1 0.36787944117144233f
#define PADK 40
#define ITERS 20

typedef __attribute__((ext_vector_type(8))) short bf16x8;
typedef __attribute__((ext_vector_type(4))) float f32x4;
typedef __attribute__((ext_vector_type(2))) float f32x2;

#define DEC0(DW) __builtin_amdgcn_cvt_pk_f32_fp8((int)(DW), false)
#define DEC1(DW) __builtin_amdgcn_cvt_pk_f32_fp8((int)(DW), true)

__device__ __forceinline__ unsigned short f2bf(float x) {
    unsigned int u = __builtin_bit_cast(unsigned int, x);
    unsigned int r = (u + 0x7FFFu + ((u >> 16) & 1u)) >> 16;
    return (unsigned short)r;
}
__device__ __forceinline__ float bf2f(unsigned short h) {
    unsigned int u = ((unsigned int)h) << 16;
    return __builtin_bit_cast(float, u);
}

// ---------------- norms: n[b][r] = sum_d d[b][r][d]^2 ----------------
__global__ __launch_bounds__(256) void norms_k(const float* __restrict__ d1,
                                               const float* __restrict__ d2,
                                               float* __restrict__ n1,
                                               float* __restrict__ n2) {
    const float* d = blockIdx.z ? d2 : d1;
    float* nn = blockIdx.z ? n2 : n1;
    int b = blockIdx.y;
    int wave = threadIdx.x >> 6, lane = threadIdx.x & 63;
    int row = blockIdx.x * 4 + wave;
    const float4 v = *(const float4*)(d + ((size_t)b * NN + row) * DD + lane * 4);
    float s = v.x * v.x + v.y * v.y + v.z * v.z + v.w * v.w;
    #pragma unroll
    for (int off = 1; off < 64; off <<= 1) s += __shfl_xor(s, off);
    if (lane == 0) nn[b * NN + row] = s;
}

// ==== MFMA: K core (fp8 e4m3) = exp(-max(n1+n2-2*dot,0)) + tile flags ====
__global__ __launch_bounds__(256) void gemm_mfma(const float* __restrict__ d1,
                                                 const float* __restrict__ d2,
                                                 const float* __restrict__ n1,
                                                 const float* __restrict__ n2,
                                                 unsigned char* __restrict__ Kc,
                                                 int* __restrict__ flags) {
    __shared__ unsigned short Ah[128 * PADK];
    __shared__ unsigned short Al[128 * PADK];
    __shared__ unsigned short Bh[128 * PADK];
    __shared__ unsigned short Bl[128 * PADK];
    __shared__ int anyf;

    const int b = blockIdx.z;
    const int n0 = blockIdx.y * 128, m0 = blockIdx.x * 128;
    const int t = threadIdx.x;
    const int wave = t >> 6, lane = t & 63;
    const int wr = (wave >> 1) * 64;
    const int wc = (wave & 1) * 64;
    const float* A  = d1 + ((size_t)b * NN + n0) * DD;
    const float* Bm = d2 + ((size_t)b * NN + m0) * DD;

    const int lrow = t >> 3;
    const int lk   = (t & 7) * 4;
    if (t == 0) anyf = 0;

    f32x4 zero = {0.f, 0.f, 0.f, 0.f};
    f32x4 acc[4][4];
    #pragma unroll
    for (int i = 0; i < 4; ++i)
        #pragma unroll
        for (int j = 0; j < 4; ++j) acc[i][j] = zero;

    const int rb = lane & 15;
    const int kg = (lane >> 4) * 8;

    for (int k0 = 0; k0 < DD; k0 += 32) {
        __syncthreads();
        #pragma unroll
        for (int rr = 0; rr < 4; ++rr) {
            int row = lrow + rr * 32;
            float4 a4 = *(const float4*)(A  + (size_t)row * DD + k0 + lk);
            float4 b4 = *(const float4*)(Bm + (size_t)row * DD + k0 + lk);
            ushort4 h, l;
            h.x = f2bf(a4.x); l.x = f2bf(a4.x - bf2f(h.x));
            h.y = f2bf(a4.y); l.y = f2bf(a4.y - bf2f(h.y));
            h.z = f2bf(a4.z); l.z = f2bf(a4.z - bf2f(h.z));
            h.w = f2bf(a4.w); l.w = f2bf(a4.w - bf2f(h.w));
            *(ushort4*)&Ah[row * PADK + lk] = h;
            *(ushort4*)&Al[row * PADK + lk] = l;
            h.x = f2bf(b4.x); l.x = f2bf(b4.x - bf2f(h.x));
            h.y = f2bf(b4.y); l.y = f2bf(b4.y - bf2f(h.y));
            h.z = f2bf(b4.z); l.z = f2bf(b4.z - bf2f(h.z));
            h.w = f2bf(b4.w); l.w = f2bf(b4.w - bf2f(h.w));
            *(ushort4*)&Bh[row * PADK + lk] = h;
            *(ushort4*)&Bl[row * PADK + lk] = l;
        }
        __syncthreads();

        bf16x8 ah[4], al[4], bh[4], bl[4];
        #pragma unroll
        for (int f = 0; f < 4; ++f) {
            int ar = (wr + f * 16 + rb) * PADK + kg;
            int br = (wc + f * 16 + rb) * PADK + kg;
            ah[f] = *(const bf16x8*)&Ah[ar];
            al[f] = *(const bf16x8*)&Al[ar];
            bh[f] = *(const bf16x8*)&Bh[br];
            bl[f] = *(const bf16x8*)&Bl[br];
        }
        #pragma unroll
        for (int i = 0; i < 4; ++i)
            #pragma unroll
            for (int j = 0; j < 4; ++j) {
                acc[i][j] = __builtin_amdgcn_mfma_f32_16x16x32_bf16(ah[i], bh[j], acc[i][j], 0, 0, 0);
                acc[i][j] = __builtin_amdgcn_mfma_f32_16x16x32_bf16(ah[i], bl[j], acc[i][j], 0, 0, 0);
                acc[i][j] = __builtin_amdgcn_mfma_f32_16x16x32_bf16(al[i], bh[j], acc[i][j], 0, 0, 0);
            }
    }

    const int rloc0 = (lane >> 4) * 4;
    int nzloc = 0;
    #pragma unroll
    for (int i = 0; i < 4; ++i) {
        #pragma unroll
        for (int jj = 0; jj < 4; ++jj) {
            int r = wr + i * 16 + rloc0 + jj;
            float rn = n1[b * NN + n0 + r];
            unsigned char* orow = Kc + ((size_t)b * NN + n0 + r) * NN + m0;
            #pragma unroll
            for (int j = 0; j < 4; ++j) {
                int c = wc + j * 16 + rb;
                float cn = n2[b * NN + m0 + c];
                float val = __expf(-fmaxf(rn + cn - 2.f * acc[i][j][jj], 0.f));
                int p = __builtin_amdgcn_cvt_pk_fp8_f32(val, val, 0, false);
                unsigned char byte = (unsigned char)(p & 0xFF);
                nzloc |= (int)byte;
                orow[c] = byte;
            }
        }
    }
    if (nzloc) anyf = 1;
    __syncthreads();
    if (t == 0) flags[b * 256 + blockIdx.y * 16 + blockIdx.x] = anyf ? 1 : 0;
}

// ========== Sinkhorn iterations: one block per batch =================
// Sparse-aware: skips all-zero 128x128 tiles of K; fully-zero K collapses
// to exact closed-form scalar recurrences (same fp operations).
__global__ __launch_bounds__(1024) void sinkhorn_iter(
    const unsigned char* __restrict__ Kc,
    const int* __restrict__ flags,
    float* __restrict__ av, float* __restrict__ bv)
{
    const int batch = blockIdx.x;
    const int t = threadIdx.x;
    const int lane = t & 63, w = t >> 6;
    __shared__ float a_sh[NN], b_sh[NN], rs_sh[NN];
    __shared__ float p8[128][9];
    __shared__ float wred[16];
    __shared__ float scal[2];
    __shared__ int flg[256];
    __shared__ int rowNZ[16], colNZ[16], anyNZ;

    if (t < 256) flg[t] = flags[batch * 256 + t];
    if (t == 0) anyNZ = 0;
    __syncthreads();
    if (t < 16) {
        int o = 0;
        #pragma unroll
        for (int j = 0; j < 16; ++j) o |= flg[t * 16 + j];
        rowNZ[t] = o;
        if (o) atomicOr(&anyNZ, 1);
    } else if (t < 32) {
        int j = t - 16, o = 0;
        #pragma unroll
        for (int i = 0; i < 16; ++i) o |= flg[i * 16 + j];
        colNZ[j] = o;
    }
    __syncthreads();
    const unsigned char* Kb = Kc + (size_t)batch * NN * NN;
    float* avb = av + (size_t)batch * AVP;
    float* bvb = bv + (size_t)batch * AVP;

    if (!anyNZ) {
        // all core K == 0: rowsum/colsum are exactly 0 -> scalar recurrences
        float bMv = 1.f, bcore = 1.f, aNv = 0.f, acore = 0.f;
        for (int it = 0; it < ITERS; ++it) {
            float Sb = 2048.f * bcore + bMv;
            aNv = 2048.f / (E1 * Sb);
            acore = 1.0f / (E1 * bMv);
            float Sa = 2048.f * acore + aNv;
            bcore = 1.0f / (E1 * aNv);
            bMv = 2048.f / (E1 * Sa);
        }
        avb[t] = acore; avb[t + 1024] = acore;
        bvb[t] = bcore; bvb[t + 1024] = bcore;
        if (t == 0) { avb[NN] = aNv; bvb[NN] = bMv; }
        return;
    }

    // ---- general (dense/mixed) path ----
    b_sh[t] = 1.f; b_sh[t + 1024] = 1.f;
    float bMv = 1.f, aNv = 0.f;
    const int r = t >> 3, c8 = (t & 7) * 16;
    __syncthreads();

    for (int it = 0; it < ITERS; ++it) {
        // Sb reduce
        float sb = b_sh[t] + b_sh[t + 1024];
        #pragma unroll
        for (int off = 1; off < 64; off <<= 1) sb += __shfl_xor(sb, off);
        if (lane == 0) wred[w] = sb;
        rs_sh[t] = 0.f; rs_sh[t + 1024] = 0.f;
        __syncthreads();
        if (t == 0) {
            float S = bMv;
            #pragma unroll
            for (int k = 0; k < 16; ++k) S += wred[k];
            scal[0] = 2048.f / (E1 * S);
        }
        __syncthreads();
        aNv = scal[0];

        // row phase: rowsum over flagged tiles
        for (int i = 0; i < 16; ++i) {
            if (!rowNZ[i]) continue;
            float acc = 0.f;
            for (int j = 0; j < 16; ++j) {
                if (!flg[i * 16 + j]) continue;
                const unsigned char* p = Kb + (size_t)(i * 128 + r) * NN + j * 128 + c8;
                uint4 kv = *(const uint4*)p;
                const float* bp = &b_sh[j * 128 + c8];
                unsigned int dwv[4] = {kv.x, kv.y, kv.z, kv.w};
                #pragma unroll
                for (int q = 0; q < 4; ++q) {
                    f32x2 u0 = DEC0(dwv[q]); f32x2 u1 = DEC1(dwv[q]);
                    acc += u0.x * bp[4 * q] + u0.y * bp[4 * q + 1]
                         + u1.x * bp[4 * q + 2] + u1.y * bp[4 * q + 3];
                }
            }
            p8[r][t & 7] = acc;
            __syncthreads();
            if (t < 128) {
                float s = 0.f;
                #pragma unroll
                for (int k = 0; k < 8; ++k) s += p8[t][k];
                rs_sh[i * 128 + t] = s;
            }
            __syncthreads();
        }
        // a update
        float ebM = E1 * bMv;
        float a0 = 1.0f / (rs_sh[t] + ebM);
        float a1 = 1.0f / (rs_sh[t + 1024] + ebM);
        a_sh[t] = a0; a_sh[t + 1024] = a1;
        // Sa reduce
        float sa = a0 + a1;
        #pragma unroll
        for (int off = 1; off < 64; off <<= 1) sa += __shfl_xor(sa, off);
        if (lane == 0) wred[w] = sa;
        __syncthreads();
        if (t == 0) {
            float S = aNv;
            #pragma unroll
            for (int k = 0; k < 16; ++k) S += wred[k];
            scal[1] = 2048.f / (E1 * S);
        }
        rs_sh[t] = 0.f; rs_sh[t + 1024] = 0.f;
        __syncthreads();

        // col phase: colsum over flagged tiles (scalar reads, fallback only)
        for (int j = 0; j < 16; ++j) {
            if (!colNZ[j]) continue;
            float acc = 0.f;
            int col = j * 128 + r;
            for (int i = 0; i < 16; ++i) {
                if (!flg[i * 16 + j]) continue;
                #pragma unroll
                for (int e = 0; e < 16; ++e) {
                    int rr2 = i * 128 + c8 + e;
                    f32x2 u = DEC0((unsigned int)Kb[(size_t)rr2 * NN + col]);
                    acc += u.x * a_sh[rr2];
                }
            }
            p8[r][t & 7] = acc;
            __syncthreads();
            if (t < 128) {
                float s = 0.f;
                #pragma unroll
                for (int k = 0; k < 8; ++k) s += p8[t][k];
                rs_sh[j * 128 + t] = s;
            }
            __syncthreads();
        }
        // b update
        float eaN = E1 * aNv;
        b_sh[t] = 1.0f / (rs_sh[t] + eaN);
        b_sh[t + 1024] = 1.0f / (rs_sh[t + 1024] + eaN);
        bMv = scal[1];
        __syncthreads();
    }
    avb[t] = a_sh[t]; avb[t + 1024] = a_sh[t + 1024];
    bvb[t] = b_sh[t]; bvb[t + 1024] = b_sh[t + 1024];
    if (t == 0) { avb[NN] = aNv; bvb[NN] = bMv; }
}

// ========== finalize: P = a_n * K * b_m (+ analytic dustbins) ========
__global__ __launch_bounds__(1024) void finalize_k(
    const unsigned char* __restrict__ Kc,
    const int* __restrict__ flags,
    const float* __restrict__ av, const float* __restrict__ bv,
    float* __restrict__ out)
{
    const int colhalf = blockIdx.x;     // 0..1
    const int rt = blockIdx.y;          // 0..15
    const int batch = blockIdx.z;
    const int t = threadIdx.x;
    const int tsub = t & 255;
    const int rq = t >> 8;              // 0..3
    const int c0 = colhalf * 1024;
    const int r0 = rt * 128;
    const float* avb = av + (size_t)batch * AVP;
    const float* bvb = bv + (size_t)batch * AVP;
    float* ob = out + (size_t)batch * NP * NP;
    const unsigned char* Kb = Kc + (size_t)batch * NN * NN;

    const int f = flags[batch * 256 + rt * 16 + colhalf * 8 + (tsub >> 5)];
    const float4 b4 = *(const float4*)&bvb[c0 + tsub * 4];
    const float bM = bvb[NN];
    const float aN = avb[NN];

    for (int rr = 0; rr < 32; ++rr) {
        int row = r0 + rr * 4 + rq;
        float4 val;
        if (f) {
            float a = avb[row];
            unsigned int kw = *(const unsigned int*)(Kb + (size_t)row * NN + c0 + tsub * 4);
            f32x2 u0 = DEC0(kw), u1 = DEC1(kw);
            val.x = a * u0.x * b4.x; val.y = a * u0.y * b4.y;
            val.z = a * u1.x * b4.z; val.w = a * u1.y * b4.w;
        } else {
            val.x = 0.f; val.y = 0.f; val.z = 0.f; val.w = 0.f;
        }
        *(float4*)&ob[(size_t)row * NP + c0 + tsub * 4] = val;
    }
    // dustbin column (index 2048)
    if (colhalf == 1 && t < 128) {
        int row = r0 + t;
        ob[(size_t)row * NP + NN] = avb[row] * E1 * bM;
    }
    // dustbin row (index 2048)
    if (rt == 0) {
        int col = c0 + t;
        ob[(size_t)NN * NP + col] = aN * E1 * bvb[col];
        if (colhalf == 1 && t == 0) ob[(size_t)NN * NP + NN] = aN * E1 * bM;
    }
}

// =====================================================================
extern "C" void kernel_launch(void* const* d_in, const int* in_sizes, int n_in,
                              void* d_out, int out_size, void* d_ws, size_t ws_size,
                              hipStream_t stream) {
    const float* d1 = (const float*)d_in[0];
    const float* d2 = (const float*)d_in[1];
    float* out = (float*)d_out;

    const size_t KCB = (size_t)BB * NN * NN;            // 33.5 MB fp8
    unsigned char* Kc = (unsigned char*)d_ws;
    int* flags = (int*)(Kc + KCB);                      // BB*256 ints
    float* av = (float*)(flags + BB * 256);             // BB*AVP
    float* bv = av + (size_t)BB * AVP;                  // BB*AVP
    float* n1 = bv + (size_t)BB * AVP;                  // BB*NN
    float* n2 = n1 + (size_t)BB * NN;                   // BB*NN

    norms_k<<<dim3(NN / 4, BB, 2), 256, 0, stream>>>(d1, d2, n1, n2);
    gemm_mfma<<<dim3(16, 16, BB), 256, 0, stream>>>(d1, d2, n1, n2, Kc, flags);
    sinkhorn_iter<<<BB, 1024, 0, stream>>>(Kc, flags, av, bv);
    finalize_k<<<dim3(2, 16, BB), 1024, 0, stream>>>(Kc, flags, av, bv, out);
}

// Round 6
// 78.543 us; speedup vs baseline: 21.8624x; 1.3862x over previous
//
#include <hip/hip_runtime.h>
#include <math.h>

#define BB 8
#define NN 2048
#define DD 256
#define NP 2049
#define AVP 2052        // padded a/b vector stride
#define E1 0.36787944117144233f
#define PADK 40         // LDS f16 row stride (80 B, 2-way conflicts only)
#define ITERS 20

typedef _Float16 f16;
typedef __attribute__((ext_vector_type(8))) _Float16 f16x8;
typedef __attribute__((ext_vector_type(4))) _Float16 f16x4;
typedef __attribute__((ext_vector_type(4))) float f32x4;
typedef __attribute__((ext_vector_type(2))) float f32x2;

#define DEC0(DW) __builtin_amdgcn_cvt_pk_f32_fp8((int)(DW), false)
#define DEC1(DW) __builtin_amdgcn_cvt_pk_f32_fp8((int)(DW), true)

// ------- split_cvt: fp32 -> fp16 copy + row norms (one wave per row) -------
__global__ __launch_bounds__(256) void split_cvt(const float* __restrict__ d1,
                                                 const float* __restrict__ d2,
                                                 f16* __restrict__ A16,
                                                 f16* __restrict__ B16,
                                                 float* __restrict__ n1,
                                                 float* __restrict__ n2) {
    const float* src = blockIdx.z ? d2 : d1;
    f16* dst = blockIdx.z ? B16 : A16;
    float* nn = blockIdx.z ? n2 : n1;
    int b = blockIdx.y;
    int wave = threadIdx.x >> 6, lane = threadIdx.x & 63;
    int row = blockIdx.x * 4 + wave;
    size_t base = ((size_t)b * NN + row) * DD;
    const float4 v = *(const float4*)(src + base + lane * 4);
    float s = v.x * v.x + v.y * v.y + v.z * v.z + v.w * v.w;
    f16x4 h;
    h.x = (f16)v.x; h.y = (f16)v.y; h.z = (f16)v.z; h.w = (f16)v.w;
    *(f16x4*)(dst + base + lane * 4) = h;
    #pragma unroll
    for (int off = 1; off < 64; off <<= 1) s += __shfl_xor(s, off);
    if (lane == 0) nn[b * NN + row] = s;
}

// ==== fp16 MFMA GEMM: K core (fp8) = exp(-max(n1+n2-2*dot,0)) + flags ====
__global__ __launch_bounds__(256) void gemm_f16(const f16* __restrict__ A16,
                                                const f16* __restrict__ B16,
                                                const float* __restrict__ n1,
                                                const float* __restrict__ n2,
                                                unsigned char* __restrict__ Kc,
                                                int* __restrict__ flags) {
    __shared__ f16 As[128 * PADK];
    __shared__ f16 Bs[128 * PADK];
    __shared__ int anyf;

    const int b = blockIdx.z;
    const int n0 = blockIdx.y * 128, m0 = blockIdx.x * 128;
    const int t = threadIdx.x;
    const int wave = t >> 6, lane = t & 63;
    const int wr = (wave >> 1) * 64;      // 2x2 wave grid, 64x64 per wave
    const int wc = (wave & 1) * 64;
    const f16* A  = A16 + ((size_t)b * NN + n0) * DD;
    const f16* Bm = B16 + ((size_t)b * NN + m0) * DD;

    const int lrow = t >> 2;              // 0..63
    const int lkw  = (t & 3) * 8;         // 0,8,16,24
    if (t == 0) anyf = 0;

    f32x4 zero = {0.f, 0.f, 0.f, 0.f};
    f32x4 acc[4][4];
    #pragma unroll
    for (int i = 0; i < 4; ++i)
        #pragma unroll
        for (int j = 0; j < 4; ++j) acc[i][j] = zero;

    const int rb = lane & 15;             // row-in-tile (A) / col-in-tile (B)
    const int kg = (lane >> 4) * 8;       // k group

    for (int k0 = 0; k0 < DD; k0 += 32) {
        // prefetch into regs, then stage
        f16x8 pa[2], pb[2];
        #pragma unroll
        for (int rr = 0; rr < 2; ++rr) {
            int row = rr * 64 + lrow;
            pa[rr] = *(const f16x8*)(A  + (size_t)row * DD + k0 + lkw);
            pb[rr] = *(const f16x8*)(Bm + (size_t)row * DD + k0 + lkw);
        }
        __syncthreads();
        #pragma unroll
        for (int rr = 0; rr < 2; ++rr) {
            int row = rr * 64 + lrow;
            *(f16x8*)&As[row * PADK + lkw] = pa[rr];
            *(f16x8*)&Bs[row * PADK + lkw] = pb[rr];
        }
        __syncthreads();

        f16x8 af[4], bf[4];
        #pragma unroll
        for (int f = 0; f < 4; ++f) {
            af[f] = *(const f16x8*)&As[(wr + f * 16 + rb) * PADK + kg];
            bf[f] = *(const f16x8*)&Bs[(wc + f * 16 + rb) * PADK + kg];
        }
        #pragma unroll
        for (int i = 0; i < 4; ++i)
            #pragma unroll
            for (int j = 0; j < 4; ++j)
                acc[i][j] = __builtin_amdgcn_mfma_f32_16x16x32_f16(af[i], bf[j], acc[i][j], 0, 0, 0);
    }

    // epilogue: D col = lane&15, row = (lane>>4)*4 + reg
    const int rloc0 = (lane >> 4) * 4;
    int nzloc = 0;
    #pragma unroll
    for (int i = 0; i < 4; ++i) {
        #pragma unroll
        for (int jj = 0; jj < 4; ++jj) {
            int r = wr + i * 16 + rloc0 + jj;
            float rn = n1[b * NN + n0 + r];
            unsigned char* orow = Kc + ((size_t)b * NN + n0 + r) * NN + m0;
            #pragma unroll
            for (int j = 0; j < 4; ++j) {
                int c = wc + j * 16 + rb;
                float cn = n2[b * NN + m0 + c];
                float val = __expf(-fmaxf(rn + cn - 2.f * acc[i][j][jj], 0.f));
                int p = __builtin_amdgcn_cvt_pk_fp8_f32(val, val, 0, false);
                unsigned char byte = (unsigned char)(p & 0xFF);
                nzloc |= (int)byte;
                orow[c] = byte;
            }
        }
    }
    if (nzloc) anyf = 1;
    __syncthreads();
    if (t == 0) flags[b * 256 + blockIdx.y * 16 + blockIdx.x] = anyf ? 1 : 0;
}

// ========== Sinkhorn iterations: one block per batch =================
__global__ __launch_bounds__(1024) void sinkhorn_iter(
    const unsigned char* __restrict__ Kc,
    const int* __restrict__ flags,
    float* __restrict__ av, float* __restrict__ bv)
{
    const int batch = blockIdx.x;
    const int t = threadIdx.x;
    const int lane = t & 63, w = t >> 6;
    __shared__ float a_sh[NN], b_sh[NN], rs_sh[NN];
    __shared__ float p8[128][9];
    __shared__ float wred[16];
    __shared__ float scal[2];
    __shared__ int flg[256];
    __shared__ int rowNZ[16], colNZ[16], anyNZ;

    if (t < 256) flg[t] = flags[batch * 256 + t];
    if (t == 0) anyNZ = 0;
    __syncthreads();
    if (t < 16) {
        int o = 0;
        #pragma unroll
        for (int j = 0; j < 16; ++j) o |= flg[t * 16 + j];
        rowNZ[t] = o;
        if (o) atomicOr(&anyNZ, 1);
    } else if (t < 32) {
        int j = t - 16, o = 0;
        #pragma unroll
        for (int i = 0; i < 16; ++i) o |= flg[i * 16 + j];
        colNZ[j] = o;
    }
    __syncthreads();
    const unsigned char* Kb = Kc + (size_t)batch * NN * NN;
    float* avb = av + (size_t)batch * AVP;
    float* bvb = bv + (size_t)batch * AVP;

    if (!anyNZ) {
        float bMv = 1.f, bcore = 1.f, aNv = 0.f, acore = 0.f;
        for (int it = 0; it < ITERS; ++it) {
            float Sb = 2048.f * bcore + bMv;
            aNv = 2048.f / (E1 * Sb);
            acore = 1.0f / (E1 * bMv);
            float Sa = 2048.f * acore + aNv;
            bcore = 1.0f / (E1 * aNv);
            bMv = 2048.f / (E1 * Sa);
        }
        avb[t] = acore; avb[t + 1024] = acore;
        bvb[t] = bcore; bvb[t + 1024] = bcore;
        if (t == 0) { avb[NN] = aNv; bvb[NN] = bMv; }
        return;
    }

    b_sh[t] = 1.f; b_sh[t + 1024] = 1.f;
    float bMv = 1.f, aNv = 0.f;
    const int r = t >> 3, c8 = (t & 7) * 16;
    __syncthreads();

    for (int it = 0; it < ITERS; ++it) {
        float sb = b_sh[t] + b_sh[t + 1024];
        #pragma unroll
        for (int off = 1; off < 64; off <<= 1) sb += __shfl_xor(sb, off);
        if (lane == 0) wred[w] = sb;
        rs_sh[t] = 0.f; rs_sh[t + 1024] = 0.f;
        __syncthreads();
        if (t == 0) {
            float S = bMv;
            #pragma unroll
            for (int k = 0; k < 16; ++k) S += wred[k];
            scal[0] = 2048.f / (E1 * S);
        }
        __syncthreads();
        aNv = scal[0];

        for (int i = 0; i < 16; ++i) {
            if (!rowNZ[i]) continue;
            float acc = 0.f;
            for (int j = 0; j < 16; ++j) {
                if (!flg[i * 16 + j]) continue;
                const unsigned char* p = Kb + (size_t)(i * 128 + r) * NN + j * 128 + c8;
                uint4 kv = *(const uint4*)p;
                const float* bp = &b_sh[j * 128 + c8];
                unsigned int dwv[4] = {kv.x, kv.y, kv.z, kv.w};
                #pragma unroll
                for (int q = 0; q < 4; ++q) {
                    f32x2 u0 = DEC0(dwv[q]); f32x2 u1 = DEC1(dwv[q]);
                    acc += u0.x * bp[4 * q] + u0.y * bp[4 * q + 1]
                         + u1.x * bp[4 * q + 2] + u1.y * bp[4 * q + 3];
                }
            }
            p8[r][t & 7] = acc;
            __syncthreads();
            if (t < 128) {
                float s = 0.f;
                #pragma unroll
                for (int k = 0; k < 8; ++k) s += p8[t][k];
                rs_sh[i * 128 + t] = s;
            }
            __syncthreads();
        }
        float ebM = E1 * bMv;
        float a0 = 1.0f / (rs_sh[t] + ebM);
        float a1 = 1.0f / (rs_sh[t + 1024] + ebM);
        a_sh[t] = a0; a_sh[t + 1024] = a1;
        float sa = a0 + a1;
        #pragma unroll
        for (int off = 1; off < 64; off <<= 1) sa += __shfl_xor(sa, off);
        if (lane == 0) wred[w] = sa;
        __syncthreads();
        if (t == 0) {
            float S = aNv;
            #pragma unroll
            for (int k = 0; k < 16; ++k) S += wred[k];
            scal[1] = 2048.f / (E1 * S);
        }
        rs_sh[t] = 0.f; rs_sh[t + 1024] = 0.f;
        __syncthreads();

        for (int j = 0; j < 16; ++j) {
            if (!colNZ[j]) continue;
            float acc = 0.f;
            int col = j * 128 + r;
            for (int i = 0; i < 16; ++i) {
                if (!flg[i * 16 + j]) continue;
                #pragma unroll
                for (int e = 0; e < 16; ++e) {
                    int rr2 = i * 128 + c8 + e;
                    f32x2 u = DEC0((unsigned int)Kb[(size_t)rr2 * NN + col]);
                    acc += u.x * a_sh[rr2];
                }
            }
            p8[r][t & 7] = acc;
            __syncthreads();
            if (t < 128) {
                float s = 0.f;
                #pragma unroll
                for (int k = 0; k < 8; ++k) s += p8[t][k];
                rs_sh[j * 128 + t] = s;
            }
            __syncthreads();
        }
        float eaN = E1 * aNv;
        b_sh[t] = 1.0f / (rs_sh[t] + eaN);
        b_sh[t + 1024] = 1.0f / (rs_sh[t + 1024] + eaN);
        bMv = scal[1];
        __syncthreads();
    }
    avb[t] = a_sh[t]; avb[t + 1024] = a_sh[t + 1024];
    bvb[t] = b_sh[t]; bvb[t + 1024] = b_sh[t + 1024];
    if (t == 0) { avb[NN] = aNv; bvb[NN] = bMv; }
}

// ========== finalize: P = a_n * K * b_m (+ analytic dustbins) ========
__global__ __launch_bounds__(1024) void finalize_k(
    const unsigned char* __restrict__ Kc,
    const int* __restrict__ flags,
    const float* __restrict__ av, const float* __restrict__ bv,
    float* __restrict__ out)
{
    const int colhalf = blockIdx.x;
    const int rt = blockIdx.y;
    const int batch = blockIdx.z;
    const int t = threadIdx.x;
    const int tsub = t & 255;
    const int rq = t >> 8;
    const int c0 = colhalf * 1024;
    const int r0 = rt * 128;
    const float* avb = av + (size_t)batch * AVP;
    const float* bvb = bv + (size_t)batch * AVP;
    float* ob = out + (size_t)batch * NP * NP;
    const unsigned char* Kb = Kc + (size_t)batch * NN * NN;

    const int f = flags[batch * 256 + rt * 16 + colhalf * 8 + (tsub >> 5)];
    const float4 b4 = *(const float4*)&bvb[c0 + tsub * 4];
    const float bM = bvb[NN];
    const float aN = avb[NN];

    for (int rr = 0; rr < 32; ++rr) {
        int row = r0 + rr * 4 + rq;
        float4 val;
        if (f) {
            float a = avb[row];
            unsigned int kw = *(const unsigned int*)(Kb + (size_t)row * NN + c0 + tsub * 4);
            f32x2 u0 = DEC0(kw), u1 = DEC1(kw);
            val.x = a * u0.x * b4.x; val.y = a * u0.y * b4.y;
            val.z = a * u1.x * b4.z; val.w = a * u1.y * b4.w;
        } else {
            val.x = 0.f; val.y = 0.f; val.z = 0.f; val.w = 0.f;
        }
        *(float4*)&ob[(size_t)row * NP + c0 + tsub * 4] = val;
    }
    if (colhalf == 1 && t < 128) {
        int row = r0 + t;
        ob[(size_t)row * NP + NN] = avb[row] * E1 * bM;
    }
    if (rt == 0) {
        int col = c0 + t;
        ob[(size_t)NN * NP + col] = aN * E1 * bvb[col];
        if (colhalf == 1 && t == 0) ob[(size_t)NN * NP + NN] = aN * E1 * bM;
    }
}

// =====================================================================
extern "C" void kernel_launch(void* const* d_in, const int* in_sizes, int n_in,
                              void* d_out, int out_size, void* d_ws, size_t ws_size,
                              hipStream_t stream) {
    const float* d1 = (const float*)d_in[0];
    const float* d2 = (const float*)d_in[1];
    float* out = (float*)d_out;

    const size_t KCB = (size_t)BB * NN * NN;            // 33.5 MB fp8
    const size_t F16C = (size_t)BB * NN * DD;           // elems per f16 array
    unsigned char* Kc = (unsigned char*)d_ws;
    f16* A16 = (f16*)(Kc + KCB);                        // 8.4 MB
    f16* B16 = A16 + F16C;                              // 8.4 MB
    int* flags = (int*)(B16 + F16C);                    // BB*256 ints
    float* av = (float*)(flags + BB * 256);             // BB*AVP
    float* bv = av + (size_t)BB * AVP;                  // BB*AVP
    float* n1 = bv + (size_t)BB * AVP;                  // BB*NN
    float* n2 = n1 + (size_t)BB * NN;                   // BB*NN

    split_cvt<<<dim3(NN / 4, BB, 2), 256, 0, stream>>>(d1, d2, A16, B16, n1, n2);
    gemm_f16<<<dim3(16, 16, BB), 256, 0, stream>>>(A16, B16, n1, n2, Kc, flags);
    sinkhorn_iter<<<BB, 1024, 0, stream>>>(Kc, flags, av, bv);
    finalize_k<<<dim3(2, 16, BB), 1024, 0, stream>>>(Kc, flags, av, bv, out);
}